// Round 2
// baseline (526.392 us; speedup 1.0000x reference)
//
#include <hip/hip_runtime.h>
#include <hip/hip_bf16.h>

#define CIN   512
#define COUT  512
#define LEN   8192
#define NB    16
#define KW    3

#define BM    128
#define BN    128
#define BKC   64
#define XROWS 132          // BN + 2 halo (+2 stage padding)
#define XROWB (BKC * 2)    // 128 B of bf16 per LDS row
#define PROWS 8200         // padded l-rows per batch in xswz (l=-1 .. 8192 + slack)

#define WB_ELEMS (COUT * CIN * KW)
#define WB_BYTES ((size_t)WB_ELEMS * 2)
#define XS_BYTES ((size_t)NB * PROWS * CIN * 2)

typedef __attribute__((ext_vector_type(4))) float f32x4;
typedef __attribute__((ext_vector_type(8))) short bf16x8;

static __device__ __forceinline__ unsigned short f2bf(float f) {
    union { float f; unsigned u; } cv; cv.f = f;
    return (unsigned short)((cv.u + 0x7fffu + ((cv.u >> 16) & 1u)) >> 16);
}

// ---- weight dequant-reorder: qweight[co][ci][t] (int32) -> wb[t][co][ci] (bf16, unscaled) ----
__global__ __launch_bounds__(256) void wconv_kernel(const int* __restrict__ q,
                                                    unsigned short* __restrict__ wb) {
    int idx = blockIdx.x * 256 + threadIdx.x;
    if (idx >= WB_ELEMS) return;
    int t  = idx >> 18;
    int r  = idx & 262143;
    int co = r >> 9;
    int ci = r & 511;
    wb[idx] = f2bf((float)q[(co * CIN + ci) * KW + t]);
}

// ---- zero the halo rows (l=-1 and l=8192) of xswz ----
__global__ __launch_bounds__(256) void zpad_kernel(unsigned short* __restrict__ xs) {
    int i = blockIdx.x * 256 + threadIdx.x;      // NB*2*CIN = 16384
    if (i >= NB * 2 * CIN) return;
    int b  = i >> 10;
    int r  = (i >> 9) & 1;
    int ci = i & 511;
    size_t p = (size_t)b * PROWS + (r ? 8193 : 0);
    xs[p * CIN + ci] = 0;
}

// ---- x prepass: fp32 [b][ci][l] -> bf16 [b][1+l][ci] (linear layout, 64x64 LDS-tiled transpose) ----
__global__ __launch_bounds__(256) void xprep_kernel(const float* __restrict__ x,
                                                    unsigned short* __restrict__ xs) {
    __shared__ char T[64 * 132];                 // ushort[64][66]-ish, 132B rows
    int blk = blockIdx.x;
    int b   = blk >> 10;                         // / (8*128)
    int ci0 = ((blk >> 7) & 7) * 64;
    int l0  = (blk & 127) * 64;
    int tid = threadIdx.x;

    const float* src = x + ((size_t)b * CIN + ci0) * LEN + l0;
    for (int i = tid; i < 64 * 16; i += 256) {
        int r = i >> 4, c4 = i & 15;
        f32x4 v = *(const f32x4*)(src + (size_t)r * LEN + c4 * 4);
        unsigned lo = (unsigned)f2bf(v[0]) | ((unsigned)f2bf(v[1]) << 16);
        unsigned hi = (unsigned)f2bf(v[2]) | ((unsigned)f2bf(v[3]) << 16);
        char* p = T + r * 132 + c4 * 8;
        *(unsigned*)p       = lo;
        *(unsigned*)(p + 4) = hi;
    }
    __syncthreads();
    unsigned short* dst = xs + ((size_t)b * PROWS + 1 + l0) * CIN + ci0;
    for (int i = tid; i < 64 * 8; i += 256) {
        int l = i >> 3, c8 = i & 7;
        union { bf16x8 v; unsigned short s[8]; } pk;
        #pragma unroll
        for (int j = 0; j < 8; ++j)
            pk.s[j] = *(const unsigned short*)(T + (c8 * 8 + j) * 132 + l * 2);
        *(bf16x8*)(dst + (size_t)l * CIN + c8 * 8) = pk.v;
    }
}

// ---- main conv: implicit GEMM, 128x128 tile, global_load_lds staging, dbuf, XOR swizzle ----
__global__ __launch_bounds__(256, 2) void conv_kernel(
    const unsigned short* __restrict__ xs,
    const unsigned short* __restrict__ wb,
    const float* __restrict__ scale_p,
    const float* __restrict__ bias,
    float* __restrict__ out)
{
    __shared__ char xT[2][XROWS * XROWB];        // 2 x 16896 B

    const int bid = blockIdx.x;
    // XCD swizzle (grid 4096 = 8*512, bijective); co varies fastest -> panel reuse in XCD L2
    const int logical = (bid & 7) * 512 + (bid >> 3);
    const int co_tile = logical & 3;
    const int n_tile  = logical >> 2;
    const int b   = n_tile >> 6;
    const int l0  = (n_tile & 63) * BN;
    const int co0 = co_tile * BM;

    const int tid  = threadIdx.x;
    const int lane = tid & 63;
    const int wid  = tid >> 6;
    const int wr = wid >> 1, wc = wid & 1;
    const int lhi = lane >> 4;
    const int llo = lane & 15;

    f32x4 acc[4][4] = {};

    // padded row p = l0 + r  (LDS row r <-> l = l0-1+r); base points at p = l0
    const char* xrow0 = (const char*)(xs + ((size_t)b * PROWS + l0) * CIN);

    // LDS stays linear; source address carries the XOR (m173 pattern). ds_read re-applies it.
#define STAGE(bufi, ci0) do {                                                              \
    const char* sb_ = xrow0 + (size_t)(ci0) * 2;                                           \
    for (int it = tid; it < XROWS * 8; it += 256) {                                        \
        int r_ = it >> 3, q_ = it & 7;                                                     \
        const char* sp_ = sb_ + (size_t)r_ * (CIN * 2) + ((q_ * 16) ^ ((r_ & 7) << 4));    \
        __builtin_amdgcn_global_load_lds(                                                  \
            (const __attribute__((address_space(1))) unsigned int*)sp_,                    \
            (__attribute__((address_space(3))) unsigned int*)(&xT[bufi][0] + it * 16),     \
            16, 0, 0);                                                                     \
    } } while (0)

#define COMPUTE(bufi, ci0) do {                                                            \
    _Pragma("unroll")                                                                      \
    for (int t_ = 0; t_ < KW; ++t_) {                                                      \
      _Pragma("unroll")                                                                    \
      for (int s_ = 0; s_ < 2; ++s_) {                                                     \
        bf16x8 af_[4];                                                                     \
        _Pragma("unroll")                                                                  \
        for (int m_ = 0; m_ < 4; ++m_)                                                     \
            af_[m_] = *(const bf16x8*)(wb +                                                \
                (size_t)(t_ * COUT + co0 + wr * 64 + m_ * 16 + llo) * CIN                  \
                + (ci0) + s_ * 32 + lhi * 8);                                              \
        bf16x8 bf_[4];                                                                     \
        _Pragma("unroll")                                                                  \
        for (int n_ = 0; n_ < 4; ++n_) {                                                   \
            int row_ = wc * 64 + n_ * 16 + llo + t_;                                       \
            int off_ = row_ * XROWB + ((s_ * 64 + lhi * 16) ^ ((row_ & 7) << 4));          \
            bf_[n_] = *(const bf16x8*)(&xT[bufi][0] + off_);                               \
        }                                                                                  \
        _Pragma("unroll")                                                                  \
        for (int m_ = 0; m_ < 4; ++m_)                                                     \
          _Pragma("unroll")                                                                \
          for (int n_ = 0; n_ < 4; ++n_)                                                   \
            acc[m_][n_] = __builtin_amdgcn_mfma_f32_16x16x32_bf16(                         \
                af_[m_], bf_[n_], acc[m_][n_], 0, 0, 0);                                   \
      }                                                                                    \
    } } while (0)

    STAGE(0, 0);
    __syncthreads();
    #pragma unroll 1
    for (int c = 0; c < CIN / BKC; ++c) {
        if (c < CIN / BKC - 1) STAGE((c + 1) & 1, (c + 1) * BKC);
        COMPUTE(c & 1, c * BKC);
        __syncthreads();
    }
#undef STAGE
#undef COMPUTE

    const float sc = scale_p[0];
    #pragma unroll
    for (int m = 0; m < 4; ++m) {
        #pragma unroll
        for (int j = 0; j < 4; ++j) {
            int co = co0 + wr * 64 + m * 16 + lhi * 4 + j;
            float bv = bias[co];
            size_t orow = ((size_t)b * COUT + co) * LEN + l0 + wc * 64;
            #pragma unroll
            for (int n = 0; n < 4; ++n)
                out[orow + n * 16 + llo] = sc * acc[m][n][j] + bv;
        }
    }
}

// ---- fallback (round-1 kernel): used only if ws_size can't hold the x prepass ----
__global__ __launch_bounds__(256, 2) void conv_fb_kernel(
    const float* __restrict__ x,
    const unsigned short* __restrict__ wb,
    const float* __restrict__ scale_p,
    const float* __restrict__ bias,
    float* __restrict__ out)
{
    __shared__ char xT[XROWS * XROWB];
    const int bid = blockIdx.x;
    const int logical = (bid & 7) * 512 + (bid >> 3);
    const int co_tile = logical & 3;
    const int n_tile  = logical >> 2;
    const int b   = n_tile >> 6;
    const int l0  = (n_tile & 63) * BN;
    const int co0 = co_tile * BM;
    const int tid  = threadIdx.x;
    const int lane = tid & 63;
    const int wid  = tid >> 6;
    const int wr = wid >> 1, wc = wid & 1;
    const int lhi = lane >> 4;
    const int llo = lane & 15;
    f32x4 acc[4][4] = {};
    const float* xb = x + (size_t)b * CIN * LEN;

    for (int ci0 = 0; ci0 < CIN; ci0 += BKC) {
        __syncthreads();
        for (int it = tid; it < XROWS * 8; it += 256) {
            int c = it % XROWS;
            int o = it / XROWS;
            int l = l0 - 1 + c;
            float v[8];
            if (l >= 0 && l < LEN) {
                const float* src = xb + (size_t)(ci0 + o * 8) * LEN + l;
                #pragma unroll
                for (int j = 0; j < 8; ++j) v[j] = src[(size_t)j * LEN];
            } else {
                #pragma unroll
                for (int j = 0; j < 8; ++j) v[j] = 0.f;
            }
            union { bf16x8 v8; unsigned short s[8]; } pk;
            #pragma unroll
            for (int j = 0; j < 8; ++j) pk.s[j] = f2bf(v[j]);
            int byte = c * XROWB + ((o * 16) ^ ((c & 7) << 4));
            *reinterpret_cast<bf16x8*>(xT + byte) = pk.v8;
        }
        __syncthreads();
        #pragma unroll
        for (int t = 0; t < KW; ++t) {
            #pragma unroll
            for (int s = 0; s < BKC / 32; ++s) {
                bf16x8 af[4];
                #pragma unroll
                for (int m = 0; m < 4; ++m)
                    af[m] = *reinterpret_cast<const bf16x8*>(
                        wb + ((size_t)t * COUT + co0 + wr * 64 + m * 16 + llo) * CIN + ci0 + s * 32 + 8 * lhi);
                bf16x8 bfr[4];
                #pragma unroll
                for (int n = 0; n < 4; ++n) {
                    int col = wc * 64 + n * 16 + llo + t;
                    int byte = col * XROWB + (((s * 32 + 8 * lhi) * 2) ^ ((col & 7) << 4));
                    bfr[n] = *reinterpret_cast<const bf16x8*>(xT + byte);
                }
                #pragma unroll
                for (int m = 0; m < 4; ++m)
                    #pragma unroll
                    for (int n = 0; n < 4; ++n)
                        acc[m][n] = __builtin_amdgcn_mfma_f32_16x16x32_bf16(af[m], bfr[n], acc[m][n], 0, 0, 0);
            }
        }
    }
    const float sc = scale_p[0];
    #pragma unroll
    for (int m = 0; m < 4; ++m) {
        #pragma unroll
        for (int j = 0; j < 4; ++j) {
            int co = co0 + wr * 64 + m * 16 + lhi * 4 + j;
            float bv = bias[co];
            size_t orow = ((size_t)b * COUT + co) * LEN + l0 + wc * 64;
            #pragma unroll
            for (int n = 0; n < 4; ++n)
                out[orow + n * 16 + llo] = sc * acc[m][n][j] + bv;
        }
    }
}

extern "C" void kernel_launch(void* const* d_in, const int* in_sizes, int n_in,
                              void* d_out, int out_size, void* d_ws, size_t ws_size,
                              hipStream_t stream) {
    const float* x    = (const float*)d_in[0];
    const int*   qw   = (const int*)d_in[1];
    const float* sc   = (const float*)d_in[2];
    const float* bias = (const float*)d_in[3];
    float* out = (float*)d_out;
    unsigned short* wb = (unsigned short*)d_ws;

    wconv_kernel<<<(WB_ELEMS + 255) / 256, 256, 0, stream>>>(qw, wb);

    if (ws_size >= WB_BYTES + XS_BYTES) {
        unsigned short* xsw = (unsigned short*)((char*)d_ws + WB_BYTES);
        zpad_kernel<<<(NB * 2 * CIN + 255) / 256, 256, 0, stream>>>(xsw);
        xprep_kernel<<<NB * 8 * (LEN / 64), 256, 0, stream>>>(x, xsw);
        conv_kernel<<<4096, 256, 0, stream>>>(xsw, wb, sc, bias, out);
    } else {
        conv_fb_kernel<<<4096, 256, 0, stream>>>(x, wb, sc, bias, out);
    }
}

// Round 3
// 375.262 us; speedup vs baseline: 1.4027x; 1.4027x over previous
//
#include <hip/hip_runtime.h>
#include <hip/hip_bf16.h>

#define CIN   512
#define COUT  512
#define LEN   8192
#define NB    16
#define KW    3
#define PROWS 8200          // padded l-rows per batch (p = l+1, l=-1..8193+slack)

#define WB_ELEMS (COUT * CIN * KW)
#define WB_BYTES ((size_t)WB_ELEMS * 2)
#define XS_BYTES ((size_t)NB * PROWS * CIN * 2)

// main-kernel tile geometry: 256x256, BK=32, 8 waves (2M x 4N), dbuf LDS 64 KB
#define BM2 256
#define BN2 256
#define BK2 32
#define NCHUNK ((CIN / BK2) * KW)     // 48, t innermost
#define TILEB  (BM2 * BK2 * 2)        // 16 KB per operand tile

typedef __attribute__((ext_vector_type(4))) float f32x4;
typedef __attribute__((ext_vector_type(8))) short bf16x8;

static __device__ __forceinline__ unsigned short f2bf(float f) {
    union { float f; unsigned u; } cv; cv.f = f;
    return (unsigned short)((cv.u + 0x7fffu + ((cv.u >> 16) & 1u)) >> 16);
}

// ---- weight dequant-reorder: qweight[co][ci][t] (int32) -> wb2[co][t*512+ci] (bf16, unscaled) ----
// A-matrix view: A[co][k], k = t*CIN + ci, contiguous in k.
__global__ __launch_bounds__(256) void wconv_kernel(const int* __restrict__ q,
                                                    unsigned short* __restrict__ wb) {
    int idx = blockIdx.x * 256 + threadIdx.x;
    if (idx >= WB_ELEMS) return;
    int co = idx / (KW * CIN);
    int r  = idx - co * (KW * CIN);
    int t  = r >> 9;
    int ci = r & 511;
    wb[idx] = f2bf((float)q[(co * CIN + ci) * KW + t]);
}

// ---- zero halo rows (l=-1 and l=8192) of xs ----
__global__ __launch_bounds__(256) void zpad_kernel(unsigned short* __restrict__ xs) {
    int i = blockIdx.x * 256 + threadIdx.x;
    if (i >= NB * 2 * CIN) return;
    int b  = i >> 10;
    int r  = (i >> 9) & 1;
    int ci = i & 511;
    size_t p = (size_t)b * PROWS + (r ? 8193 : 0);
    xs[p * CIN + ci] = 0;
}

// ---- x prepass: fp32 [b][ci][l] -> bf16 [b][1+l][ci] (64x64 LDS-tiled transpose) ----
__global__ __launch_bounds__(256) void xprep_kernel(const float* __restrict__ x,
                                                    unsigned short* __restrict__ xs) {
    __shared__ char T[64 * 132];
    int blk = blockIdx.x;
    int b   = blk >> 10;
    int ci0 = ((blk >> 7) & 7) * 64;
    int l0  = (blk & 127) * 64;
    int tid = threadIdx.x;

    const float* src = x + ((size_t)b * CIN + ci0) * LEN + l0;
    for (int i = tid; i < 64 * 16; i += 256) {
        int r = i >> 4, c4 = i & 15;
        f32x4 v = *(const f32x4*)(src + (size_t)r * LEN + c4 * 4);
        unsigned lo = (unsigned)f2bf(v[0]) | ((unsigned)f2bf(v[1]) << 16);
        unsigned hi = (unsigned)f2bf(v[2]) | ((unsigned)f2bf(v[3]) << 16);
        char* p = T + r * 132 + c4 * 8;
        *(unsigned*)p       = lo;
        *(unsigned*)(p + 4) = hi;
    }
    __syncthreads();
    unsigned short* dst = xs + ((size_t)b * PROWS + 1 + l0) * CIN + ci0;
    for (int i = tid; i < 64 * 8; i += 256) {
        int l = i >> 3, c8 = i & 7;
        union { bf16x8 v; unsigned short s[8]; } pk;
        #pragma unroll
        for (int j = 0; j < 8; ++j)
            pk.s[j] = *(const unsigned short*)(T + (c8 * 8 + j) * 132 + l * 2);
        *(bf16x8*)(dst + (size_t)l * CIN + c8 * 8) = pk.v;
    }
}

// ---- main conv: 256x256 GEMM tile, BK=32, both operands via global_load_lds, dbuf ----
__global__ __launch_bounds__(512, 2) void conv_kernel(
    const unsigned short* __restrict__ xs,
    const unsigned short* __restrict__ wb,
    const float* __restrict__ scale_p,
    const float* __restrict__ bias,
    float* __restrict__ out)
{
    __shared__ char sA[2][TILEB];    // 2 x 16 KB
    __shared__ char sB[2][TILEB];    // 2 x 16 KB

    const int bid = blockIdx.x;
    // XCD swizzle: grid 1024 = 8*128 exact; co fastest -> co-pair shares x panel in XCD L2
    const int logical = (bid & 7) * 128 + (bid >> 3);
    const int co_tile = logical & 1;
    const int l_tile  = logical >> 1;            // 0..511
    const int b   = l_tile >> 5;                 // 32 l-tiles per batch
    const int l0  = (l_tile & 31) * BN2;
    const int co0 = co_tile * BM2;

    const int tid  = threadIdx.x;
    const int lane = tid & 63;
    const int wid  = tid >> 6;                   // 0..7
    const int wr   = wid >> 2;                   // 0..1  (M half: 128 rows)
    const int wc   = wid & 3;                    // 0..3  (N quarter: 64 cols)
    const int lhi  = lane >> 4;
    const int llo  = lane & 15;

    f32x4 acc[8][4] = {};                        // wave tile 128(M) x 64(N)

    const char* wbB = (const char*)wb;
    const char* xsB = (const char*)(xs + ((size_t)b * PROWS + l0) * CIN);

    // chunk c: t = c % 3 (innermost -> consecutive chunks reuse x rows in L2),
    //          ci0 = (c/3)*32; k-offset in A = t*CIN + ci0
#define STAGE(bufi, c_) do {                                                                 \
    int t_   = (c_) % KW;                                                                    \
    int ci0_ = ((c_) / KW) * BK2;                                                            \
    const char* asrc_ = wbB + (size_t)co0 * (KW * CIN * 2) + (t_ * CIN + ci0_) * 2;          \
    const char* bsrc_ = xsB + ((size_t)t_ * CIN + ci0_) * 2;                                 \
    _Pragma("unroll")                                                                        \
    for (int k_ = 0; k_ < 2; ++k_) {                                                         \
        int it_ = tid + k_ * 512;                                                            \
        int r_  = it_ >> 2, q_ = it_ & 3;                                                    \
        int sw_ = (q_ * 16) ^ ((r_ & 3) << 4);                                               \
        __builtin_amdgcn_global_load_lds(                                                    \
            (const __attribute__((address_space(1))) unsigned int*)                          \
                (asrc_ + (size_t)r_ * (KW * CIN * 2) + sw_),                                 \
            (__attribute__((address_space(3))) unsigned int*)(&sA[bufi][0] + it_ * 16),      \
            16, 0, 0);                                                                       \
        __builtin_amdgcn_global_load_lds(                                                    \
            (const __attribute__((address_space(1))) unsigned int*)                          \
                (bsrc_ + (size_t)r_ * (CIN * 2) + sw_),                                      \
            (__attribute__((address_space(3))) unsigned int*)(&sB[bufi][0] + it_ * 16),      \
            16, 0, 0);                                                                       \
    } } while (0)

#define COMPUTE(bufi) do {                                                                   \
    bf16x8 af_[8];                                                                           \
    _Pragma("unroll")                                                                        \
    for (int m_ = 0; m_ < 8; ++m_) {                                                         \
        int row_ = wr * 128 + m_ * 16 + llo;                                                 \
        af_[m_] = *(const bf16x8*)(&sA[bufi][0] + row_ * 64                                  \
                                   + ((lhi * 16) ^ ((row_ & 3) << 4)));                      \
    }                                                                                        \
    bf16x8 bf_[4];                                                                           \
    _Pragma("unroll")                                                                        \
    for (int n_ = 0; n_ < 4; ++n_) {                                                         \
        int row_ = wc * 64 + n_ * 16 + llo;                                                  \
        bf_[n_] = *(const bf16x8*)(&sB[bufi][0] + row_ * 64                                  \
                                   + ((lhi * 16) ^ ((row_ & 3) << 4)));                      \
    }                                                                                        \
    __builtin_amdgcn_s_setprio(1);                                                           \
    _Pragma("unroll")                                                                        \
    for (int m_ = 0; m_ < 8; ++m_)                                                           \
        _Pragma("unroll")                                                                    \
        for (int n_ = 0; n_ < 4; ++n_)                                                       \
            acc[m_][n_] = __builtin_amdgcn_mfma_f32_16x16x32_bf16(                           \
                af_[m_], bf_[n_], acc[m_][n_], 0, 0, 0);                                     \
    __builtin_amdgcn_s_setprio(0);                                                           \
    } while (0)

    STAGE(0, 0);
    __syncthreads();
    #pragma unroll 1
    for (int c = 0; c < NCHUNK; ++c) {
        if (c < NCHUNK - 1) STAGE((c + 1) & 1, c + 1);
        COMPUTE(c & 1);
        __syncthreads();
    }
#undef STAGE
#undef COMPUTE

    const float sc = scale_p[0];
    #pragma unroll
    for (int m = 0; m < 8; ++m) {
        #pragma unroll
        for (int j = 0; j < 4; ++j) {
            int co = co0 + wr * 128 + m * 16 + lhi * 4 + j;
            float bv = bias[co];
            size_t orow = ((size_t)b * COUT + co) * LEN + l0 + wc * 64;
            #pragma unroll
            for (int n = 0; n < 4; ++n)
                out[orow + n * 16 + llo] = sc * acc[m][n][j] + bv;
        }
    }
}

// ---- fallback (no x prepass; reg-staged conversion) — only if ws too small ----
__global__ __launch_bounds__(256, 2) void conv_fb_kernel(
    const float* __restrict__ x,
    const unsigned short* __restrict__ wb,
    const float* __restrict__ scale_p,
    const float* __restrict__ bias,
    float* __restrict__ out)
{
    __shared__ char xT[132 * 128];
    const int bid = blockIdx.x;
    const int logical = (bid & 7) * 512 + (bid >> 3);
    const int co_tile = logical & 3;
    const int n_tile  = logical >> 2;
    const int b   = n_tile >> 6;
    const int l0  = (n_tile & 63) * 128;
    const int co0 = co_tile * 128;
    const int tid  = threadIdx.x;
    const int lane = tid & 63;
    const int wid  = tid >> 6;
    const int wr = wid >> 1, wc = wid & 1;
    const int lhi = lane >> 4;
    const int llo = lane & 15;
    f32x4 acc[4][4] = {};
    const float* xb = x + (size_t)b * CIN * LEN;

    for (int ci0 = 0; ci0 < CIN; ci0 += 64) {
        __syncthreads();
        for (int it = tid; it < 132 * 8; it += 256) {
            int c = it % 132;
            int o = it / 132;
            int l = l0 - 1 + c;
            float v[8];
            if (l >= 0 && l < LEN) {
                const float* src = xb + (size_t)(ci0 + o * 8) * LEN + l;
                #pragma unroll
                for (int j = 0; j < 8; ++j) v[j] = src[(size_t)j * LEN];
            } else {
                #pragma unroll
                for (int j = 0; j < 8; ++j) v[j] = 0.f;
            }
            union { bf16x8 v8; unsigned short s[8]; } pk;
            #pragma unroll
            for (int j = 0; j < 8; ++j) pk.s[j] = f2bf(v[j]);
            int byte = c * 128 + ((o * 16) ^ ((c & 7) << 4));
            *reinterpret_cast<bf16x8*>(xT + byte) = pk.v8;
        }
        __syncthreads();
        #pragma unroll
        for (int t = 0; t < KW; ++t) {
            #pragma unroll
            for (int s = 0; s < 2; ++s) {
                bf16x8 af[4];
                #pragma unroll
                for (int m = 0; m < 4; ++m)
                    af[m] = *reinterpret_cast<const bf16x8*>(
                        wb + (size_t)(co0 + wr * 64 + m * 16 + llo) * (KW * CIN)
                           + t * CIN + ci0 + s * 32 + 8 * lhi);
                bf16x8 bfr[4];
                #pragma unroll
                for (int n = 0; n < 4; ++n) {
                    int col = wc * 64 + n * 16 + llo + t;
                    int byte = col * 128 + (((s * 32 + 8 * lhi) * 2) ^ ((col & 7) << 4));
                    bfr[n] = *reinterpret_cast<const bf16x8*>(xT + byte);
                }
                #pragma unroll
                for (int m = 0; m < 4; ++m)
                    #pragma unroll
                    for (int n = 0; n < 4; ++n)
                        acc[m][n] = __builtin_amdgcn_mfma_f32_16x16x32_bf16(af[m], bfr[n], acc[m][n], 0, 0, 0);
            }
        }
    }
    const float sc = scale_p[0];
    #pragma unroll
    for (int m = 0; m < 4; ++m) {
        #pragma unroll
        for (int j = 0; j < 4; ++j) {
            int co = co0 + wr * 64 + m * 16 + lhi * 4 + j;
            float bv = bias[co];
            size_t orow = ((size_t)b * COUT + co) * LEN + l0 + wc * 64;
            #pragma unroll
            for (int n = 0; n < 4; ++n)
                out[orow + n * 16 + llo] = sc * acc[m][n][j] + bv;
        }
    }
}

extern "C" void kernel_launch(void* const* d_in, const int* in_sizes, int n_in,
                              void* d_out, int out_size, void* d_ws, size_t ws_size,
                              hipStream_t stream) {
    const float* x    = (const float*)d_in[0];
    const int*   qw   = (const int*)d_in[1];
    const float* sc   = (const float*)d_in[2];
    const float* bias = (const float*)d_in[3];
    float* out = (float*)d_out;
    unsigned short* wb = (unsigned short*)d_ws;

    wconv_kernel<<<(WB_ELEMS + 255) / 256, 256, 0, stream>>>(qw, wb);

    if (ws_size >= WB_BYTES + XS_BYTES) {
        unsigned short* xsw = (unsigned short*)((char*)d_ws + WB_BYTES);
        zpad_kernel<<<(NB * 2 * CIN + 255) / 256, 256, 0, stream>>>(xsw);
        xprep_kernel<<<NB * 8 * (LEN / 64), 256, 0, stream>>>(x, xsw);
        conv_kernel<<<(COUT / BM2) * (NB * LEN / BN2), 512, 0, stream>>>(xsw, wb, sc, bias, out);
    } else {
        conv_fb_kernel<<<4096, 256, 0, stream>>>(x, wb, sc, bias, out);
    }
}

// Round 4
// 297.368 us; speedup vs baseline: 1.7702x; 1.2619x over previous
//
#include <hip/hip_runtime.h>
#include <hip/hip_bf16.h>

#define CIN   512
#define COUT  512
#define LEN   8192
#define NB    16
#define KW    3
#define PROWS 8200          // padded l-rows per batch (p = l+1, l=-1..8193+slack)

#define WB_ELEMS (COUT * CIN * KW)
#define WB_BYTES ((size_t)WB_ELEMS * 2)
#define XS_BYTES ((size_t)NB * PROWS * CIN * 2)

// main kernel: 256x256 tile, BK=64, 8 waves (2Mx4N), 8-phase counted-vmcnt schedule
#define BM2 256
#define BN2 256
#define BK3 64
#define NT  ((CIN / BK3) * KW)        // 24 K-tiles, tap innermost
#define TILE3 (BM2 * BK3 * 2)         // 32 KB per operand tile

typedef __attribute__((ext_vector_type(4))) float f32x4;
typedef __attribute__((ext_vector_type(8))) short bf16x8;

static __device__ __forceinline__ unsigned short f2bf(float f) {
    union { float f; unsigned u; } cv; cv.f = f;
    return (unsigned short)((cv.u + 0x7fffu + ((cv.u >> 16) & 1u)) >> 16);
}

// ---- weight dequant-reorder: qweight[co][ci][t] (int32) -> wb[co][t*512+ci] (bf16) ----
__global__ __launch_bounds__(256) void wconv_kernel(const int* __restrict__ q,
                                                    unsigned short* __restrict__ wb) {
    int idx = blockIdx.x * 256 + threadIdx.x;
    if (idx >= WB_ELEMS) return;
    int co = idx / (KW * CIN);
    int r  = idx - co * (KW * CIN);
    int t  = r >> 9;
    int ci = r & 511;
    wb[idx] = f2bf((float)q[(co * CIN + ci) * KW + t]);
}

// ---- zero halo rows (l=-1 and l=8192) of xs ----
__global__ __launch_bounds__(256) void zpad_kernel(unsigned short* __restrict__ xs) {
    int i = blockIdx.x * 256 + threadIdx.x;
    if (i >= NB * 2 * CIN) return;
    int b  = i >> 10;
    int r  = (i >> 9) & 1;
    int ci = i & 511;
    size_t p = (size_t)b * PROWS + (r ? 8193 : 0);
    xs[p * CIN + ci] = 0;
}

// ---- x prepass: fp32 [b][ci][l] -> bf16 [b][1+l][ci] (64x64 LDS-tiled transpose) ----
__global__ __launch_bounds__(256) void xprep_kernel(const float* __restrict__ x,
                                                    unsigned short* __restrict__ xs) {
    __shared__ char T[64 * 132];
    int blk = blockIdx.x;
    int b   = blk >> 10;
    int ci0 = ((blk >> 7) & 7) * 64;
    int l0  = (blk & 127) * 64;
    int tid = threadIdx.x;

    const float* src = x + ((size_t)b * CIN + ci0) * LEN + l0;
    for (int i = tid; i < 64 * 16; i += 256) {
        int r = i >> 4, c4 = i & 15;
        f32x4 v = *(const f32x4*)(src + (size_t)r * LEN + c4 * 4);
        unsigned lo = (unsigned)f2bf(v[0]) | ((unsigned)f2bf(v[1]) << 16);
        unsigned hi = (unsigned)f2bf(v[2]) | ((unsigned)f2bf(v[3]) << 16);
        char* p = T + r * 132 + c4 * 8;
        *(unsigned*)p       = lo;
        *(unsigned*)(p + 4) = hi;
    }
    __syncthreads();
    unsigned short* dst = xs + ((size_t)b * PROWS + 1 + l0) * CIN + ci0;
    for (int i = tid; i < 64 * 8; i += 256) {
        int l = i >> 3, c8 = i & 7;
        union { bf16x8 v; unsigned short s[8]; } pk;
        #pragma unroll
        for (int j = 0; j < 8; ++j)
            pk.s[j] = *(const unsigned short*)(T + (c8 * 8 + j) * 132 + l * 2);
        *(bf16x8*)(dst + (size_t)l * CIN + c8 * 8) = pk.v;
    }
}

// ---- main conv: 8-phase counted-vmcnt schedule ----
__global__ __launch_bounds__(512, 2) void conv_kernel(
    const unsigned short* __restrict__ xs,
    const unsigned short* __restrict__ wb,
    const float* __restrict__ scale_p,
    const float* __restrict__ bias,
    float* __restrict__ out)
{
    __shared__ char sA[2][TILE3];    // 2 x 32 KB
    __shared__ char sB[2][TILE3];    // 2 x 32 KB   (128 KiB total)

    const int bid = blockIdx.x;
    const int logical = (bid & 7) * 128 + (bid >> 3);   // XCD swizzle, 1024 = 8*128
    const int co_tile = logical & 1;
    const int l_tile  = logical >> 1;
    const int b   = l_tile >> 5;
    const int l0  = (l_tile & 31) * BN2;
    const int co0 = co_tile * BM2;

    const int tid  = threadIdx.x;
    const int lane = tid & 63;
    const int wid  = tid >> 6;
    const int wr   = wid >> 2;        // 0..1
    const int wc   = wid & 3;         // 0..3
    const int lhi  = lane >> 4;
    const int llo  = lane & 15;

    f32x4 acc[8][4] = {};             // row = m_*32 + wr*16 (interleaved map)

    const char* xsB = (const char*)(xs + ((size_t)b * PROWS + l0) * CIN);
    const char* wbB = (const char*)wb + (size_t)co0 * (KW * CIN * 2);

    // stage unit u of K-tile c into buf: u0=B rows0-127, u1=B rows128-255, u2=A h0, u3=A h1
#define STAGEU(buf_, c_, u_) do {                                                            \
    int tap_ = (c_) % KW;  int ci0_ = ((c_) / KW) * BK3;                                     \
    int rowoff_ = ((u_) & 1) * 128;                                                          \
    const char* src0_; size_t rstride_; char* dst0_;                                         \
    if ((u_) < 2) { src0_ = xsB + ((size_t)(tap_ + rowoff_) * CIN + ci0_) * 2;               \
                    rstride_ = CIN * 2; dst0_ = &sB[buf_][rowoff_ * 128]; }                   \
    else          { src0_ = wbB + (size_t)rowoff_ * (KW * CIN * 2)                           \
                            + ((size_t)tap_ * CIN + ci0_) * 2;                               \
                    rstride_ = KW * CIN * 2; dst0_ = &sA[buf_][rowoff_ * 128]; }             \
    _Pragma("unroll")                                                                        \
    for (int kk_ = 0; kk_ < 2; ++kk_) {                                                      \
        int it_ = tid + kk_ * 512;                                                           \
        int r_ = it_ >> 3, q_ = it_ & 7;                                                     \
        __builtin_amdgcn_global_load_lds(                                                    \
            (const __attribute__((address_space(1))) unsigned int*)                          \
                (src0_ + (size_t)r_ * rstride_ + ((q_ * 16) ^ ((r_ & 7) << 4))),             \
            (__attribute__((address_space(3))) unsigned int*)(dst0_ + it_ * 16),             \
            16, 0, 0);                                                                       \
    } } while (0)

#define LDA(d_, buf_, mq_, k_) do { int row_ = (mq_) * 32 + wr * 16 + llo;                   \
    d_ = *(const bf16x8*)(&sA[buf_][0] + row_ * 128                                          \
                          + (((k_) * 64 + lhi * 16) ^ ((row_ & 7) << 4))); } while (0)
#define LDB(d_, buf_, n_, k_) do { int row_ = wc * 64 + (n_) * 16 + llo;                     \
    d_ = *(const bf16x8*)(&sB[buf_][0] + row_ * 128                                          \
                          + (((k_) * 64 + lhi * 16) ^ ((row_ & 7) << 4))); } while (0)

#define MFMA16(p_) do {                                                                      \
    __builtin_amdgcn_s_setprio(1);                                                           \
    acc[2*(p_)  ][0] = __builtin_amdgcn_mfma_f32_16x16x32_bf16(a0_, bB00, acc[2*(p_)  ][0],0,0,0); \
    acc[2*(p_)  ][1] = __builtin_amdgcn_mfma_f32_16x16x32_bf16(a0_, bB10, acc[2*(p_)  ][1],0,0,0); \
    acc[2*(p_)  ][2] = __builtin_amdgcn_mfma_f32_16x16x32_bf16(a0_, bB20, acc[2*(p_)  ][2],0,0,0); \
    acc[2*(p_)  ][3] = __builtin_amdgcn_mfma_f32_16x16x32_bf16(a0_, bB30, acc[2*(p_)  ][3],0,0,0); \
    acc[2*(p_)+1][0] = __builtin_amdgcn_mfma_f32_16x16x32_bf16(a2_, bB00, acc[2*(p_)+1][0],0,0,0); \
    acc[2*(p_)+1][1] = __builtin_amdgcn_mfma_f32_16x16x32_bf16(a2_, bB10, acc[2*(p_)+1][1],0,0,0); \
    acc[2*(p_)+1][2] = __builtin_amdgcn_mfma_f32_16x16x32_bf16(a2_, bB20, acc[2*(p_)+1][2],0,0,0); \
    acc[2*(p_)+1][3] = __builtin_amdgcn_mfma_f32_16x16x32_bf16(a2_, bB30, acc[2*(p_)+1][3],0,0,0); \
    acc[2*(p_)  ][0] = __builtin_amdgcn_mfma_f32_16x16x32_bf16(a1_, bB01, acc[2*(p_)  ][0],0,0,0); \
    acc[2*(p_)  ][1] = __builtin_amdgcn_mfma_f32_16x16x32_bf16(a1_, bB11, acc[2*(p_)  ][1],0,0,0); \
    acc[2*(p_)  ][2] = __builtin_amdgcn_mfma_f32_16x16x32_bf16(a1_, bB21, acc[2*(p_)  ][2],0,0,0); \
    acc[2*(p_)  ][3] = __builtin_amdgcn_mfma_f32_16x16x32_bf16(a1_, bB31, acc[2*(p_)  ][3],0,0,0); \
    acc[2*(p_)+1][0] = __builtin_amdgcn_mfma_f32_16x16x32_bf16(a3_, bB01, acc[2*(p_)+1][0],0,0,0); \
    acc[2*(p_)+1][1] = __builtin_amdgcn_mfma_f32_16x16x32_bf16(a3_, bB11, acc[2*(p_)+1][1],0,0,0); \
    acc[2*(p_)+1][2] = __builtin_amdgcn_mfma_f32_16x16x32_bf16(a3_, bB21, acc[2*(p_)+1][2],0,0,0); \
    acc[2*(p_)+1][3] = __builtin_amdgcn_mfma_f32_16x16x32_bf16(a3_, bB31, acc[2*(p_)+1][3],0,0,0); \
    __builtin_amdgcn_s_setprio(0);                                                           \
    } while (0)

#define BAR()    __builtin_amdgcn_s_barrier()
#define SCHED0() __builtin_amdgcn_sched_barrier(0)
#define LGKM0()  asm volatile("s_waitcnt lgkmcnt(0)" ::: "memory")

    // prologue: stage all 4 units of tile 0; first 3 must land before p0 reads
    STAGEU(0, 0, 0); STAGEU(0, 0, 1); STAGEU(0, 0, 2); STAGEU(0, 0, 3);
    asm volatile("s_waitcnt vmcnt(2)" ::: "memory");
    BAR();

    bf16x8 bB00, bB01, bB10, bB11, bB20, bB21, bB30, bB31;
    bf16x8 a0_, a1_, a2_, a3_;

    #pragma unroll 1
    for (int c = 0; c < NT - 1; ++c) {
        const int buf = c & 1, nb = buf ^ 1;
        // ---- phase 0: read all B + A quadrant 0; stage Bh0(next) ----
        SCHED0();
        LDB(bB00, buf, 0, 0); LDB(bB01, buf, 0, 1);
        LDB(bB10, buf, 1, 0); LDB(bB11, buf, 1, 1);
        LDB(bB20, buf, 2, 0); LDB(bB21, buf, 2, 1);
        LDB(bB30, buf, 3, 0); LDB(bB31, buf, 3, 1);
        LDA(a0_, buf, 0, 0); LDA(a1_, buf, 0, 1); LDA(a2_, buf, 1, 0); LDA(a3_, buf, 1, 1);
        STAGEU(nb, c + 1, 0);
        BAR(); LGKM0(); SCHED0();
        MFMA16(0);
        BAR();
        // ---- phase 1: A quadrant 1; stage Bh1(next); wait for Ah1(cur) ----
        SCHED0();
        LDA(a0_, buf, 2, 0); LDA(a1_, buf, 2, 1); LDA(a2_, buf, 3, 0); LDA(a3_, buf, 3, 1);
        STAGEU(nb, c + 1, 1);
        asm volatile("s_waitcnt vmcnt(4)" ::: "memory");
        BAR(); LGKM0(); SCHED0();
        MFMA16(1);
        BAR();
        // ---- phase 2: A quadrant 2; stage Ah0(next) ----
        SCHED0();
        LDA(a0_, buf, 4, 0); LDA(a1_, buf, 4, 1); LDA(a2_, buf, 5, 0); LDA(a3_, buf, 5, 1);
        STAGEU(nb, c + 1, 2);
        BAR(); LGKM0(); SCHED0();
        MFMA16(2);
        BAR();
        // ---- phase 3: A quadrant 3; stage Ah1(next); wait for Bh0,Bh1,Ah0(next) ----
        SCHED0();
        LDA(a0_, buf, 6, 0); LDA(a1_, buf, 6, 1); LDA(a2_, buf, 7, 0); LDA(a3_, buf, 7, 1);
        STAGEU(nb, c + 1, 3);
        asm volatile("s_waitcnt vmcnt(2)" ::: "memory");
        BAR(); LGKM0(); SCHED0();
        MFMA16(3);
        BAR();
    }
    // ---- peeled tail tile (no stages); drain Ah1 with vmcnt(0) before quadrant 2 ----
    {
        const int buf = (NT - 1) & 1;
        SCHED0();
        LDB(bB00, buf, 0, 0); LDB(bB01, buf, 0, 1);
        LDB(bB10, buf, 1, 0); LDB(bB11, buf, 1, 1);
        LDB(bB20, buf, 2, 0); LDB(bB21, buf, 2, 1);
        LDB(bB30, buf, 3, 0); LDB(bB31, buf, 3, 1);
        LDA(a0_, buf, 0, 0); LDA(a1_, buf, 0, 1); LDA(a2_, buf, 1, 0); LDA(a3_, buf, 1, 1);
        BAR(); LGKM0(); SCHED0();
        MFMA16(0);
        BAR();
        SCHED0();
        LDA(a0_, buf, 2, 0); LDA(a1_, buf, 2, 1); LDA(a2_, buf, 3, 0); LDA(a3_, buf, 3, 1);
        asm volatile("s_waitcnt vmcnt(0)" ::: "memory");
        BAR(); LGKM0(); SCHED0();
        MFMA16(1);
        BAR();
        SCHED0();
        LDA(a0_, buf, 4, 0); LDA(a1_, buf, 4, 1); LDA(a2_, buf, 5, 0); LDA(a3_, buf, 5, 1);
        BAR(); LGKM0(); SCHED0();
        MFMA16(2);
        BAR();
        SCHED0();
        LDA(a0_, buf, 6, 0); LDA(a1_, buf, 6, 1); LDA(a2_, buf, 7, 0); LDA(a3_, buf, 7, 1);
        LGKM0(); SCHED0();
        MFMA16(3);
    }
#undef STAGEU
#undef LDA
#undef LDB
#undef MFMA16

    const float sc = scale_p[0];
    #pragma unroll
    for (int m = 0; m < 8; ++m) {
        #pragma unroll
        for (int j = 0; j < 4; ++j) {
            int co = co0 + m * 32 + wr * 16 + lhi * 4 + j;
            float bv = bias[co];
            size_t orow = ((size_t)b * COUT + co) * LEN + l0 + wc * 64;
            #pragma unroll
            for (int n = 0; n < 4; ++n)
                out[orow + n * 16 + llo] = sc * acc[m][n][j] + bv;
        }
    }
}

// ---- fallback (no x prepass) — only if ws too small ----
__global__ __launch_bounds__(256, 2) void conv_fb_kernel(
    const float* __restrict__ x,
    const unsigned short* __restrict__ wb,
    const float* __restrict__ scale_p,
    const float* __restrict__ bias,
    float* __restrict__ out)
{
    __shared__ char xT[132 * 128];
    const int bid = blockIdx.x;
    const int logical = (bid & 7) * 512 + (bid >> 3);
    const int co_tile = logical & 3;
    const int n_tile  = logical >> 2;
    const int b   = n_tile >> 6;
    const int l0  = (n_tile & 63) * 128;
    const int co0 = co_tile * 128;
    const int tid  = threadIdx.x;
    const int lane = tid & 63;
    const int wid  = tid >> 6;
    const int wr = wid >> 1, wc = wid & 1;
    const int lhi = lane >> 4;
    const int llo = lane & 15;
    f32x4 acc[4][4] = {};
    const float* xb = x + (size_t)b * CIN * LEN;

    for (int ci0 = 0; ci0 < CIN; ci0 += 64) {
        __syncthreads();
        for (int it = tid; it < 132 * 8; it += 256) {
            int c = it % 132;
            int o = it / 132;
            int l = l0 - 1 + c;
            float v[8];
            if (l >= 0 && l < LEN) {
                const float* src = xb + (size_t)(ci0 + o * 8) * LEN + l;
                #pragma unroll
                for (int j = 0; j < 8; ++j) v[j] = src[(size_t)j * LEN];
            } else {
                #pragma unroll
                for (int j = 0; j < 8; ++j) v[j] = 0.f;
            }
            union { bf16x8 v8; unsigned short s[8]; } pk;
            #pragma unroll
            for (int j = 0; j < 8; ++j) pk.s[j] = f2bf(v[j]);
            int byte = c * 128 + ((o * 16) ^ ((c & 7) << 4));
            *reinterpret_cast<bf16x8*>(xT + byte) = pk.v8;
        }
        __syncthreads();
        #pragma unroll
        for (int t = 0; t < KW; ++t) {
            #pragma unroll
            for (int s = 0; s < 2; ++s) {
                bf16x8 af[4];
                #pragma unroll
                for (int m = 0; m < 4; ++m)
                    af[m] = *reinterpret_cast<const bf16x8*>(
                        wb + (size_t)(co0 + wr * 64 + m * 16 + llo) * (KW * CIN)
                           + t * CIN + ci0 + s * 32 + 8 * lhi);
                bf16x8 bfr[4];
                #pragma unroll
                for (int n = 0; n < 4; ++n) {
                    int col = wc * 64 + n * 16 + llo + t;
                    int byte = col * 128 + (((s * 32 + 8 * lhi) * 2) ^ ((col & 7) << 4));
                    bfr[n] = *reinterpret_cast<const bf16x8*>(xT + byte);
                }
                #pragma unroll
                for (int m = 0; m < 4; ++m)
                    #pragma unroll
                    for (int n = 0; n < 4; ++n)
                        acc[m][n] = __builtin_amdgcn_mfma_f32_16x16x32_bf16(af[m], bfr[n], acc[m][n], 0, 0, 0);
            }
        }
    }
    const float sc = scale_p[0];
    #pragma unroll
    for (int m = 0; m < 4; ++m) {
        #pragma unroll
        for (int j = 0; j < 4; ++j) {
            int co = co0 + wr * 64 + m * 16 + lhi * 4 + j;
            float bv = bias[co];
            size_t orow = ((size_t)b * COUT + co) * LEN + l0 + wc * 64;
            #pragma unroll
            for (int n = 0; n < 4; ++n)
                out[orow + n * 16 + llo] = sc * acc[m][n][j] + bv;
        }
    }
}

extern "C" void kernel_launch(void* const* d_in, const int* in_sizes, int n_in,
                              void* d_out, int out_size, void* d_ws, size_t ws_size,
                              hipStream_t stream) {
    const float* x    = (const float*)d_in[0];
    const int*   qw   = (const int*)d_in[1];
    const float* sc   = (const float*)d_in[2];
    const float* bias = (const float*)d_in[3];
    float* out = (float*)d_out;
    unsigned short* wb = (unsigned short*)d_ws;

    wconv_kernel<<<(WB_ELEMS + 255) / 256, 256, 0, stream>>>(qw, wb);

    if (ws_size >= WB_BYTES + XS_BYTES) {
        unsigned short* xsw = (unsigned short*)((char*)d_ws + WB_BYTES);
        zpad_kernel<<<(NB * 2 * CIN + 255) / 256, 256, 0, stream>>>(xsw);
        xprep_kernel<<<NB * 8 * (LEN / 64), 256, 0, stream>>>(x, xsw);
        conv_kernel<<<(COUT / BM2) * (NB * LEN / BN2), 512, 0, stream>>>(xsw, wb, sc, bias, out);
    } else {
        conv_fb_kernel<<<4096, 256, 0, stream>>>(x, wb, sc, bias, out);
    }
}